// Round 11
// baseline (421.381 us; speedup 1.0000x reference)
//
#include <hip/hip_runtime.h>

#define BATCH 262144
#define MARGIN 1e-5f
#define LIST_CAP (1u<<20)

typedef __attribute__((ext_vector_type(8))) short short8;
typedef __attribute__((ext_vector_type(16))) float f32x16;

// ---------------- workspace layout (bytes) ----------------
// 0       : Rt64 f64[128][128]  Rt64[j*128+k] = R[k][j]      (131072)
// 131072  : img  u16: i1h[16384] i1l[16384] i2h[16384] i2l[16384] (131072)
// 262144  : counter u32
// 262912  : list u32[LIST_CAP]                                (4 MB)
// 4457216 : M64 f64[128][128]   I+A (exact)                   (131072)
// 4588288 : Y64 f64[128][128]   f32-GJ inverse                (131072)
// 4719360 : Yb  f64[128][128]   Newton intermediate           (131072)

__device__ __forceinline__ unsigned f2bf(float f) {
  unsigned u = __float_as_uint(f);
  return (u + 0x7FFFu + ((u >> 16) & 1u)) >> 16;   // RTN-even bf16
}

// =======================================================================
// K_pre32: f32 Gauss-Jordan inversion of M = I + A (no pivoting; sym
// part of every Schur complement is I => pivots >= 1). Round-9 exact
// form: spilled-but-fastest structure (publish touches ONE element in a
// rare branch; select-chain variants re-read all 16 spilled elements
// every iter and were 1.5-3x slower). Y64 accuracy non-critical: kref's
// two f64 Newton steps square the residual to ~1e-15.
// Also zeroes the patch counter (saves a memset dispatch).
// =======================================================================
__global__ __launch_bounds__(1024)
void kpre32(const float* __restrict__ skew, double* __restrict__ M64,
            double* __restrict__ Y64, unsigned int* __restrict__ counter)
{
  __shared__ float colk[2][128];
  __shared__ float pivrow[128];
  const int tid = threadIdx.x;
  const int i = tid >> 3;
  const int s = tid & 7;
  if (tid == 0) *counter = 0;

  float M[16];
  #pragma unroll
  for (int e = 0; e < 16; ++e) {
    int j = s + 8*e;
    float v;
    if (i == j)      v = 1.0f;
    else if (i < j)  v =  skew[i*127 - (i*(i-1))/2 + (j - i - 1)];
    else             v = -skew[j*127 - (j*(j-1))/2 + (i - j - 1)];
    M[e] = v;
    M64[i*128 + j] = (double)v;     // exact I+A
  }
  if (s == 0) colk[0][i] = M[0];
  __syncthreads();

  for (int k = 0; k < 128; ++k) {
    const int p = k & 1, np = p ^ 1;
    const int ns = (k + 1) & 7, ne = (k + 1) >> 3;
    if (i == k) {
      float rec = 1.0f / colk[p][k];
      #pragma unroll
      for (int e = 0; e < 16; ++e) {
        int j = s + 8*e;
        float v = (j == k) ? 1.0f : M[e];
        v *= rec;
        M[e] = v;
        pivrow[j] = v;
      }
      if (s == ns && k < 127) colk[np][i] = M[ne];
    }
    __syncthreads();
    if (i != k) {
      float f = colk[p][i];
      #pragma unroll
      for (int e = 0; e < 16; ++e) {
        int j = s + 8*e;
        float v = (j == k) ? 0.0f : M[e];
        M[e] = fmaf(-f, pivrow[j], v);
      }
      if (s == ns && k < 127) colk[np][i] = M[ne];
    }
    __syncthreads();
  }

  #pragma unroll
  for (int e = 0; e < 16; ++e) {
    int j = s + 8*e;
    Y64[i*128 + j] = (double)M[e];
  }
}

// =======================================================================
// K_ref: one f64 Newton-Schulz step Yout = Yin*(2I - M64*Yin), per
// 16-column tile (8 blocks). final_pass: emit R = 2*Y2 - I as Rt64 +
// bf16-split fragment images.
// =======================================================================
__global__ __launch_bounds__(256, 2)
void kref(const double* __restrict__ M64, const double* __restrict__ Yin,
          double* __restrict__ Yout, double* __restrict__ Rt64,
          unsigned short* __restrict__ img, const int final_pass)
{
  __shared__ double Yc[128][17];
  __shared__ double T[128][17];
  const int t = threadIdx.x;
  const int c0 = blockIdx.x * 16;

  #pragma unroll
  for (int u = 0; u < 8; ++u) {
    int idx = u*256 + t;
    int row = idx >> 4, cc = idx & 15;
    Yc[row][cc] = Yin[row*128 + c0 + cc];
  }
  __syncthreads();

  const int m = t >> 1;
  const int h = (t & 1) * 8;

  double a0=0,a1=0,a2=0,a3=0,a4=0,a5=0,a6=0,a7=0;
  for (int j = 0; j < 128; ++j) {
    double mv = M64[m*128 + j];
    a0 = fma(mv, Yc[j][h+0], a0);  a1 = fma(mv, Yc[j][h+1], a1);
    a2 = fma(mv, Yc[j][h+2], a2);  a3 = fma(mv, Yc[j][h+3], a3);
    a4 = fma(mv, Yc[j][h+4], a4);  a5 = fma(mv, Yc[j][h+5], a5);
    a6 = fma(mv, Yc[j][h+6], a6);  a7 = fma(mv, Yc[j][h+7], a7);
  }
  T[m][h+0]=a0; T[m][h+1]=a1; T[m][h+2]=a2; T[m][h+3]=a3;
  T[m][h+4]=a4; T[m][h+5]=a5; T[m][h+6]=a6; T[m][h+7]=a7;
  __syncthreads();

  double b0=0,b1=0,b2=0,b3=0,b4=0,b5=0,b6=0,b7=0;
  for (int j = 0; j < 128; ++j) {
    double yv = Yin[m*128 + j];
    b0 = fma(yv, T[j][h+0], b0);  b1 = fma(yv, T[j][h+1], b1);
    b2 = fma(yv, T[j][h+2], b2);  b3 = fma(yv, T[j][h+3], b3);
    b4 = fma(yv, T[j][h+4], b4);  b5 = fma(yv, T[j][h+5], b5);
    b6 = fma(yv, T[j][h+6], b6);  b7 = fma(yv, T[j][h+7], b7);
  }

  double y2[8] = { 2.0*Yc[m][h+0]-b0, 2.0*Yc[m][h+1]-b1, 2.0*Yc[m][h+2]-b2,
                   2.0*Yc[m][h+3]-b3, 2.0*Yc[m][h+4]-b4, 2.0*Yc[m][h+5]-b5,
                   2.0*Yc[m][h+6]-b6, 2.0*Yc[m][h+7]-b7 };

  if (!final_pass) {
    #pragma unroll
    for (int c = 0; c < 8; ++c) Yout[m*128 + c0 + h + c] = y2[c];
  } else {
    #pragma unroll
    for (int c = 0; c < 8; ++c) {
      const int i = m, j = c0 + h + c;
      double v = 2.0*y2[c] - ((i == j) ? 1.0 : 0.0);    // R[i][j]
      Rt64[j*128 + i] = v;
      float r32 = (float)v;
      unsigned hh = f2bf(r32);
      unsigned ll = f2bf(r32 - __uint_as_float(hh << 16));
      int off1 = (((i>>5)*8 + (j>>4))*64 + ((((j>>3)&1)<<5) | (i&31)))*8 + (j&7);
      img[off1]          = (unsigned short)hh;
      img[16384 + off1]  = (unsigned short)ll;
      int off2 = (((j>>5)*8 + (i>>4))*64 + ((((i>>3)&1)<<5) | (j&31)))*8 + (i&7);
      img[32768 + off2]  = (unsigned short)hh;
      img[49152 + off2]  = (unsigned short)ll;
    }
  }
}

// =======================================================================
// K_main: fused rotate+quantize+reconstruct. 1024 blocks x 256 thr.
// Occupancy push: X/Q SINGLE-buffered (lgkm-drain barriers make dbuf
// redundant: every buffer's last reader drains at the intervening
// barrier), B1 fragments in registers, B2 fragments streamed from
// global (L2-resident) in phase C. waves_per_eu(3) caps regs ~170 ->
// 3 blocks/CU (12 waves/CU vs 8 before). norms/invs stay double-
// buffered (phase-C read vs next phase-A write race otherwise).
// =======================================================================
#define MM3(ACC, XH, XL, BH, BL)                                        \
  ACC = __builtin_amdgcn_mfma_f32_32x32x16_bf16(XH, BH, ACC, 0, 0, 0);  \
  ACC = __builtin_amdgcn_mfma_f32_32x32x16_bf16(XL, BH, ACC, 0, 0, 0);  \
  ACC = __builtin_amdgcn_mfma_f32_32x32x16_bf16(XH, BL, ACC, 0, 0, 0);

#define LGKM_BAR()                                                      \
  asm volatile("s_waitcnt lgkmcnt(0)" ::: "memory");                    \
  __builtin_amdgcn_s_barrier();                                         \
  __builtin_amdgcn_sched_barrier(0);

__global__ __attribute__((amdgpu_waves_per_eu(3)))  __launch_bounds__(256)
void kmain(const float* __restrict__ x, const float* __restrict__ mean,
           const float* __restrict__ cent, const unsigned short* __restrict__ img,
           float* __restrict__ out,
           unsigned int* __restrict__ counter, unsigned int* __restrict__ list)
{
  __shared__ __align__(16) unsigned short Xh[32*128];   // 8 KB (swizzled)
  __shared__ __align__(16) unsigned short Xl[32*128];
  __shared__ __align__(16) unsigned short Qh[32*128];
  __shared__ __align__(16) unsigned short Ql[32*128];
  __shared__ float norms[2][4][32];
  __shared__ float invs[2][4][32];

  const int tid = threadIdx.x, lane = tid & 63, w = tid >> 6;
  const int al = lane & 31, ah = lane >> 5;

  // B1 fragments (mm1) resident in registers; B2 streamed per use.
  short8 B1h[8], B1l[8];
  #pragma unroll
  for (int t = 0; t < 8; ++t) {
    size_t o = (size_t)((w*8 + t)*64 + lane)*8;
    B1h[t] = *(const short8*)(img +         o);
    B1l[t] = *(const short8*)(img + 16384 + o);
  }
  const unsigned short* i2h = img + 32768;
  const unsigned short* i2l = img + 49152;

  const float c0 = cent[0], c1 = cent[1], c2 = cent[2], c3 = cent[3];
  const float c4 = cent[4], c5 = cent[5], c6 = cent[6], c7 = cent[7];
  const float mid0 = 0.5f*(c0+c1), mid1 = 0.5f*(c1+c2), mid2 = 0.5f*(c2+c3),
              mid3 = 0.5f*(c3+c4), mid4 = 0.5f*(c4+c5), mid5 = 0.5f*(c5+c6),
              mid6 = 0.5f*(c6+c7);
  unsigned qt0, qt1, qt2, qt3, qt4, qt5, qt6, qt7;
  {
    #define PS(C, QT) { unsigned h = f2bf(C); float hf = __uint_as_float(h<<16); \
                        QT = (h<<16) | f2bf((C) - hf); }
    PS(c0,qt0) PS(c1,qt1) PS(c2,qt2) PS(c3,qt3)
    PS(c4,qt4) PS(c5,qt5) PS(c6,qt6) PS(c7,qt7)
    #undef PS
  }

  const float2 mean2 = *(const float2*)(mean + 2*lane);
  const float meanv = mean[w*32 + al];

  const int row0 = blockIdx.x * 256;

  float2 xpf[8];
  #pragma unroll
  for (int rr = 0; rr < 8; ++rr)
    xpf[rr] = *(const float2*)(x + (size_t)(row0 + w*8 + rr)*128 + 2*lane);

  const bool own = (((al >> 2) & 1) == ah);
  const int rrq = al - 4*ah;
  const int gsel = (rrq & 3) + 4*(rrq >> 3);

  for (int ch = 0; ch < 8; ++ch) {
    const int chb = row0 + ch*32;
    const int p = ch & 1;

    // ---- Phase A: issue next-chunk loads; cvt_pk split -> X ----
    float2 xn[8];
    if (ch < 7) {
      #pragma unroll
      for (int rr = 0; rr < 8; ++rr)
        xn[rr] = *(const float2*)(x + (size_t)(chb + 32 + w*8 + rr)*128 + 2*lane);
    }
    #pragma unroll
    for (int rr = 0; rr < 8; ++rr) {
      const int r = w*8 + rr;
      float a = xpf[rr].x - mean2.x;
      float b = xpf[rr].y - mean2.y;
      unsigned ph, pl;
      asm("v_cvt_pk_bf16_f32 %0, %1, %2" : "=v"(ph) : "v"(a), "v"(b));
      float ha = __uint_as_float(ph << 16);
      float hb = __uint_as_float(ph & 0xFFFF0000u);
      float ra = a - ha, rb = b - hb;
      asm("v_cvt_pk_bf16_f32 %0, %1, %2" : "=v"(pl) : "v"(ra), "v"(rb));
      unsigned off = ((unsigned)(r*256 + 4*lane)) ^ (((unsigned)(r & 7)) << 4);
      *(unsigned*)((char*)Xh + off) = ph;
      *(unsigned*)((char*)Xl + off) = pl;
    }
    #pragma unroll
    for (int rr = 0; rr < 8; ++rr) xpf[rr] = xn[rr];
    LGKM_BAR();                                       // bar1: X ready

    // ---- Phase B: norm-MFMA + mm1, quantize, write Q ----
    f32x16 accN, accA, accB;
    #pragma unroll
    for (int g = 0; g < 16; ++g) { accN[g] = 0.0f; accA[g] = 0.0f; accB[g] = 0.0f; }
    __builtin_amdgcn_s_setprio(1);
    #pragma unroll
    for (int t = 0; t < 8; ++t) {
      unsigned fb = ((unsigned)(al*256 + t*32 + ah*16)) ^ (((unsigned)(al & 7)) << 4);
      short8 xh = *(const short8*)((const char*)Xh + fb);
      short8 xl = *(const short8*)((const char*)Xl + fb);
      accN = __builtin_amdgcn_mfma_f32_32x32x16_bf16(xh, xh, accN, 0, 0, 0);
      accN = __builtin_amdgcn_mfma_f32_32x32x16_bf16(xl, xh, accN, 0, 0, 0);
      accN = __builtin_amdgcn_mfma_f32_32x32x16_bf16(xh, xl, accN, 0, 0, 0);
      if (t & 1) { MM3(accB, xh, xl, B1h[t], B1l[t]); }
      else       { MM3(accA, xh, xl, B1h[t], B1l[t]); }
    }
    __builtin_amdgcn_s_setprio(0);
    #pragma unroll
    for (int g = 0; g < 16; ++g) accA[g] += accB[g];

    // diag -> norms/invs (per-wave LDS broadcast)
    {
      float s2 = accN[0];
      #pragma unroll
      for (int e = 1; e < 16; ++e) s2 = (gsel == e) ? accN[e] : s2;
      if (own) {
        float n = fmaxf(sqrtf(s2), 1e-8f);
        norms[p][w][al] = n;
        invs[p][w][al]  = 1.0f / n;
      }
    }
    asm volatile("s_waitcnt lgkmcnt(0)" ::: "memory");

    unsigned qp[16];
    unsigned flags = 0;
    #pragma unroll
    for (int g = 0; g < 16; ++g) {
      const int r = (g & 3) + 8*(g >> 2) + 4*ah;
      float xr = accA[g] * invs[p][w][r];
      unsigned q = qt0;
      q = (xr > mid0) ? qt1 : q;  q = (xr > mid1) ? qt2 : q;
      q = (xr > mid2) ? qt3 : q;  q = (xr > mid3) ? qt4 : q;
      q = (xr > mid4) ? qt5 : q;  q = (xr > mid5) ? qt6 : q;
      q = (xr > mid6) ? qt7 : q;
      float dm = fabsf(xr - mid0);
      dm = fminf(dm, fabsf(xr - mid1)); dm = fminf(dm, fabsf(xr - mid2));
      dm = fminf(dm, fabsf(xr - mid3)); dm = fminf(dm, fabsf(xr - mid4));
      dm = fminf(dm, fabsf(xr - mid5)); dm = fminf(dm, fabsf(xr - mid6));
      qp[g] = q;
      flags |= (dm < MARGIN) ? (1u << g) : 0u;
    }
    #pragma unroll
    for (int g = 0; g < 16; ++g) {
      const int rq = (g & 3) + 8*(g >> 2) + 4*ah;
      unsigned off = ((unsigned)(rq*256 + (w*32 + al)*2)) ^ (((unsigned)(rq & 7)) << 4);
      *(unsigned short*)((char*)Qh + off) = (unsigned short)(qp[g] >> 16);
      *(unsigned short*)((char*)Ql + off) = (unsigned short)(qp[g] & 0xFFFFu);
    }
    if (__builtin_amdgcn_ballot_w64(flags != 0)) {   // rare path
      #pragma unroll
      for (int g = 0; g < 16; ++g) {
        unsigned long long b = __ballot((flags >> g) & 1u);
        if (b) {
          const int rq = (g & 3) + 8*(g >> 2) + 4*ah;
          unsigned base = 0;
          if (lane == 0) base = atomicAdd(counter, (unsigned)__popcll(b));
          base = (unsigned)__shfl((int)base, 0);
          if ((flags >> g) & 1u) {
            unsigned pp = base + (unsigned)__popcll(b & ((1ull << lane) - 1ull));
            if (pp < LIST_CAP) list[pp] = (unsigned)(chb + rq);
          }
        }
      }
    }
    LGKM_BAR();                                       // bar2: Q ready

    // ---- Phase C: mm2 (Q x B2 streamed from L2), scale + store ----
    f32x16 acc2, acc3;
    #pragma unroll
    for (int g = 0; g < 16; ++g) { acc2[g] = 0.0f; acc3[g] = 0.0f; }
    __builtin_amdgcn_s_setprio(1);
    #pragma unroll
    for (int t = 0; t < 8; ++t) {
      size_t o = (size_t)((w*8 + t)*64 + lane)*8;
      short8 bh = *(const short8*)(i2h + o);
      short8 bl = *(const short8*)(i2l + o);
      unsigned fb = ((unsigned)(al*256 + t*32 + ah*16)) ^ (((unsigned)(al & 7)) << 4);
      short8 xh = *(const short8*)((const char*)Qh + fb);
      short8 xl = *(const short8*)((const char*)Ql + fb);
      if (t & 1) { MM3(acc3, xh, xl, bh, bl); }
      else       { MM3(acc2, xh, xl, bh, bl); }
    }
    __builtin_amdgcn_s_setprio(0);

    #pragma unroll
    for (int g = 0; g < 16; ++g) {
      const int rq = (g & 3) + 8*(g >> 2) + 4*ah;
      float o = fmaf(acc2[g] + acc3[g], norms[p][w][rq], meanv);
      out[(size_t)(chb + rq)*128 + w*32 + al] = o;
    }
  }
}

// =======================================================================
// K_fix: exact f64 recompute of rows with any element within MARGIN of
// a quantization midpoint. One wave per row; overwrites out.
// =======================================================================
__global__ __launch_bounds__(256)
void kfix(const float* __restrict__ x, const float* __restrict__ mean,
          const float* __restrict__ cent, const double* __restrict__ Rt64,
          float* __restrict__ out,
          const unsigned int* __restrict__ counter,
          const unsigned int* __restrict__ list)
{
  __shared__ double xs[4][128];
  __shared__ double qs[4][128];
  const int tid = threadIdx.x, lane = tid & 63, w = tid >> 6;

  unsigned cnt = *counter;
  if (cnt > LIST_CAP) cnt = LIST_CAP;

  const double cc0 = (double)cent[0], cc1 = (double)cent[1], cc2 = (double)cent[2],
               cc3 = (double)cent[3], cc4 = (double)cent[4], cc5 = (double)cent[5],
               cc6 = (double)cent[6], cc7 = (double)cent[7];
  const double m0 = 0.5*(cc0+cc1), m1 = 0.5*(cc1+cc2), m2 = 0.5*(cc2+cc3),
               m3 = 0.5*(cc3+cc4), m4 = 0.5*(cc4+cc5), m5 = 0.5*(cc5+cc6),
               m6 = 0.5*(cc6+cc7);

  const unsigned gw = blockIdx.x*4 + w, stride = gridDim.x*4;
  for (unsigned e = gw; e < cnt; e += stride) {
    const int row = (int)list[e];
    const float* xr = x + (size_t)row*128;
    const int j0 = 2*lane;

    double a = (double)xr[j0]   - (double)mean[j0];
    double b = (double)xr[j0+1] - (double)mean[j0+1];
    double s = a*a + b*b;
    s += __shfl_xor(s, 1);  s += __shfl_xor(s, 2);  s += __shfl_xor(s, 4);
    s += __shfl_xor(s, 8);  s += __shfl_xor(s, 16); s += __shfl_xor(s, 32);
    double n = sqrt(s);
    if (n < 1e-8) n = 1e-8;
    double inv = 1.0 / n;
    xs[w][j0]   = a * inv;
    xs[w][j0+1] = b * inv;
    asm volatile("s_waitcnt lgkmcnt(0)" ::: "memory");

    double acc0 = 0.0, acc1 = 0.0;
    for (int j = 0; j < 128; ++j) {
      double xj = xs[w][j];
      acc0 = fma(xj, Rt64[j*128 + j0],     acc0);
      acc1 = fma(xj, Rt64[j*128 + j0 + 1], acc1);
    }
    double q0 = cc0;
    q0 = (acc0 > m0) ? cc1 : q0;  q0 = (acc0 > m1) ? cc2 : q0;
    q0 = (acc0 > m2) ? cc3 : q0;  q0 = (acc0 > m3) ? cc4 : q0;
    q0 = (acc0 > m4) ? cc5 : q0;  q0 = (acc0 > m5) ? cc6 : q0;
    q0 = (acc0 > m6) ? cc7 : q0;
    double q1 = cc0;
    q1 = (acc1 > m0) ? cc1 : q1;  q1 = (acc1 > m1) ? cc2 : q1;
    q1 = (acc1 > m2) ? cc3 : q1;  q1 = (acc1 > m3) ? cc4 : q1;
    q1 = (acc1 > m4) ? cc5 : q1;  q1 = (acc1 > m5) ? cc6 : q1;
    q1 = (acc1 > m6) ? cc7 : q1;
    qs[w][j0]   = q0;
    qs[w][j0+1] = q1;
    asm volatile("s_waitcnt lgkmcnt(0)" ::: "memory");

    double o0 = 0.0, o1 = 0.0;
    for (int k = 0; k < 128; ++k) {
      double qk = qs[w][k];
      o0 = fma(qk, Rt64[j0*128 + k],       o0);
      o1 = fma(qk, Rt64[(j0+1)*128 + k],   o1);
    }
    out[(size_t)row*128 + j0]   = (float)fma(o0, n, (double)mean[j0]);
    out[(size_t)row*128 + j0+1] = (float)fma(o1, n, (double)mean[j0+1]);
  }
}

// =======================================================================
extern "C" void kernel_launch(void* const* d_in, const int* in_sizes, int n_in,
                              void* d_out, int out_size, void* d_ws, size_t ws_size,
                              hipStream_t stream)
{
  (void)in_sizes; (void)n_in; (void)out_size; (void)ws_size;
  const float* x    = (const float*)d_in[0];
  const float* skew = (const float*)d_in[1];
  const float* cent = (const float*)d_in[2];
  const float* mean = (const float*)d_in[3];
  float* out = (float*)d_out;

  char* ws = (char*)d_ws;
  double*         Rt64 = (double*)(ws);
  unsigned short* img  = (unsigned short*)(ws + 131072);
  unsigned int*   cntr = (unsigned int*)(ws + 262144);
  unsigned int*   list = (unsigned int*)(ws + 262912);
  double*         M64  = (double*)(ws + 4457216);
  double*         Y64  = (double*)(ws + 4588288);
  double*         Yb   = (double*)(ws + 4719360);

  kpre32<<<dim3(1),    dim3(1024), 0, stream>>>(skew, M64, Y64, cntr);
  kref  <<<dim3(8),    dim3(256),  0, stream>>>(M64, Y64, Yb, Rt64, img, 0);
  kref  <<<dim3(8),    dim3(256),  0, stream>>>(M64, Yb, Y64, Rt64, img, 1);
  kmain <<<dim3(1024), dim3(256),  0, stream>>>(x, mean, cent, img, out, cntr, list);
  kfix  <<<dim3(256),  dim3(256),  0, stream>>>(x, mean, cent, Rt64, out, cntr, list);
}

// Round 12
// 272.687 us; speedup vs baseline: 1.5453x; 1.5453x over previous
//
#include <hip/hip_runtime.h>

#define BATCH 262144
#define MARGIN 1e-5f
#define LIST_CAP (1u<<20)

typedef __attribute__((ext_vector_type(8))) short short8;
typedef __attribute__((ext_vector_type(16))) float f32x16;

// ---------------- workspace layout (bytes) ----------------
// 0       : Rt64 f64[128][128]  Rt64[j*128+k] = R[k][j]      (131072)
// 131072  : img  u16: i1h[16384] i1l[16384] i2h[16384] i2l[16384] (131072)
// 262144  : counter u32
// 262912  : list u32[LIST_CAP]                                (4 MB)
// 4457216 : M64 f64[128][128]   I+A (exact)                   (131072)
// 4588288 : Y64 f64[128][128]   f32-GJ inverse                (131072)
// 4719360 : Yb  f64[128][128]   Newton intermediate           (131072)

__device__ __forceinline__ unsigned f2bf(float f) {
  unsigned u = __float_as_uint(f);
  return (u + 0x7FFFu + ((u >> 16) & 1u)) >> 16;   // RTN-even bf16
}

// =======================================================================
// K_pre32: f32 Gauss-Jordan inversion of M = I + A (no pivoting; sym
// part of every Schur complement is I => pivots >= 1). Round-9 exact
// structure (fastest measured spilled form). NEW: amdgpu_waves_per_eu
// (4,4) -- max=4 tells the allocator one resident 1024-thr block is the
// ceiling -> 128-VGPR budget (launch_bounds(1024,4) min-only was a
// no-op in round 7; round 11 proved this attribute family does rebudget).
// Y64 accuracy non-critical: kref's two f64 Newton steps square the
// residual to ~1e-15. Also zeroes the patch counter.
// =======================================================================
__global__ __attribute__((amdgpu_waves_per_eu(4, 4))) __launch_bounds__(1024)
void kpre32(const float* __restrict__ skew, double* __restrict__ M64,
            double* __restrict__ Y64, unsigned int* __restrict__ counter)
{
  __shared__ float colk[2][128];
  __shared__ float pivrow[128];
  const int tid = threadIdx.x;
  const int i = tid >> 3;
  const int s = tid & 7;
  if (tid == 0) *counter = 0;

  float M[16];
  #pragma unroll
  for (int e = 0; e < 16; ++e) {
    int j = s + 8*e;
    float v;
    if (i == j)      v = 1.0f;
    else if (i < j)  v =  skew[i*127 - (i*(i-1))/2 + (j - i - 1)];
    else             v = -skew[j*127 - (j*(j-1))/2 + (i - j - 1)];
    M[e] = v;
    M64[i*128 + j] = (double)v;     // exact I+A
  }
  if (s == 0) colk[0][i] = M[0];
  __syncthreads();

  for (int k = 0; k < 128; ++k) {
    const int p = k & 1, np = p ^ 1;
    const int ns = (k + 1) & 7, ne = (k + 1) >> 3;
    if (i == k) {
      float rec = 1.0f / colk[p][k];
      #pragma unroll
      for (int e = 0; e < 16; ++e) {
        int j = s + 8*e;
        float v = (j == k) ? 1.0f : M[e];
        v *= rec;
        M[e] = v;
        pivrow[j] = v;
      }
      if (s == ns && k < 127) colk[np][i] = M[ne];
    }
    __syncthreads();
    if (i != k) {
      float f = colk[p][i];
      #pragma unroll
      for (int e = 0; e < 16; ++e) {
        int j = s + 8*e;
        float v = (j == k) ? 0.0f : M[e];
        M[e] = fmaf(-f, pivrow[j], v);
      }
      if (s == ns && k < 127) colk[np][i] = M[ne];
    }
    __syncthreads();
  }

  #pragma unroll
  for (int e = 0; e < 16; ++e) {
    int j = s + 8*e;
    Y64[i*128 + j] = (double)M[e];
  }
}

// =======================================================================
// K_ref: one f64 Newton-Schulz step Yout = Yin*(2I - M64*Yin), per
// 16-column tile (8 blocks). final_pass: emit R = 2*Y2 - I as Rt64 +
// bf16-split fragment images.
// =======================================================================
__global__ __launch_bounds__(256, 2)
void kref(const double* __restrict__ M64, const double* __restrict__ Yin,
          double* __restrict__ Yout, double* __restrict__ Rt64,
          unsigned short* __restrict__ img, const int final_pass)
{
  __shared__ double Yc[128][17];
  __shared__ double T[128][17];
  const int t = threadIdx.x;
  const int c0 = blockIdx.x * 16;

  #pragma unroll
  for (int u = 0; u < 8; ++u) {
    int idx = u*256 + t;
    int row = idx >> 4, cc = idx & 15;
    Yc[row][cc] = Yin[row*128 + c0 + cc];
  }
  __syncthreads();

  const int m = t >> 1;
  const int h = (t & 1) * 8;

  double a0=0,a1=0,a2=0,a3=0,a4=0,a5=0,a6=0,a7=0;
  for (int j = 0; j < 128; ++j) {
    double mv = M64[m*128 + j];
    a0 = fma(mv, Yc[j][h+0], a0);  a1 = fma(mv, Yc[j][h+1], a1);
    a2 = fma(mv, Yc[j][h+2], a2);  a3 = fma(mv, Yc[j][h+3], a3);
    a4 = fma(mv, Yc[j][h+4], a4);  a5 = fma(mv, Yc[j][h+5], a5);
    a6 = fma(mv, Yc[j][h+6], a6);  a7 = fma(mv, Yc[j][h+7], a7);
  }
  T[m][h+0]=a0; T[m][h+1]=a1; T[m][h+2]=a2; T[m][h+3]=a3;
  T[m][h+4]=a4; T[m][h+5]=a5; T[m][h+6]=a6; T[m][h+7]=a7;
  __syncthreads();

  double b0=0,b1=0,b2=0,b3=0,b4=0,b5=0,b6=0,b7=0;
  for (int j = 0; j < 128; ++j) {
    double yv = Yin[m*128 + j];
    b0 = fma(yv, T[j][h+0], b0);  b1 = fma(yv, T[j][h+1], b1);
    b2 = fma(yv, T[j][h+2], b2);  b3 = fma(yv, T[j][h+3], b3);
    b4 = fma(yv, T[j][h+4], b4);  b5 = fma(yv, T[j][h+5], b5);
    b6 = fma(yv, T[j][h+6], b6);  b7 = fma(yv, T[j][h+7], b7);
  }

  double y2[8] = { 2.0*Yc[m][h+0]-b0, 2.0*Yc[m][h+1]-b1, 2.0*Yc[m][h+2]-b2,
                   2.0*Yc[m][h+3]-b3, 2.0*Yc[m][h+4]-b4, 2.0*Yc[m][h+5]-b5,
                   2.0*Yc[m][h+6]-b6, 2.0*Yc[m][h+7]-b7 };

  if (!final_pass) {
    #pragma unroll
    for (int c = 0; c < 8; ++c) Yout[m*128 + c0 + h + c] = y2[c];
  } else {
    #pragma unroll
    for (int c = 0; c < 8; ++c) {
      const int i = m, j = c0 + h + c;
      double v = 2.0*y2[c] - ((i == j) ? 1.0 : 0.0);    // R[i][j]
      Rt64[j*128 + i] = v;
      float r32 = (float)v;
      unsigned hh = f2bf(r32);
      unsigned ll = f2bf(r32 - __uint_as_float(hh << 16));
      int off1 = (((i>>5)*8 + (j>>4))*64 + ((((j>>3)&1)<<5) | (i&31)))*8 + (j&7);
      img[off1]          = (unsigned short)hh;
      img[16384 + off1]  = (unsigned short)ll;
      int off2 = (((j>>5)*8 + (i>>4))*64 + ((((i>>3)&1)<<5) | (j&31)))*8 + (i&7);
      img[32768 + off2]  = (unsigned short)hh;
      img[49152 + off2]  = (unsigned short)ll;
    }
  }
}

// =======================================================================
// K_main: round-10 form (best measured): 1024 blocks x 256 thr,
// B1+B2 fragments in registers, X/Q LDS double-buffered, lgkm-only
// barriers, norms via MFMA X.X^T diagonal, cvt_pk bf16 split staging.
// launch_bounds(256,2): 2 waves/SIMD, 256-VGPR budget -- no spills.
// =======================================================================
#define MM3(ACC, XH, XL, BH, BL)                                        \
  ACC = __builtin_amdgcn_mfma_f32_32x32x16_bf16(XH, BH, ACC, 0, 0, 0);  \
  ACC = __builtin_amdgcn_mfma_f32_32x32x16_bf16(XL, BH, ACC, 0, 0, 0);  \
  ACC = __builtin_amdgcn_mfma_f32_32x32x16_bf16(XH, BL, ACC, 0, 0, 0);

#define LGKM_BAR()                                                      \
  asm volatile("s_waitcnt lgkmcnt(0)" ::: "memory");                    \
  __builtin_amdgcn_s_barrier();                                         \
  __builtin_amdgcn_sched_barrier(0);

__global__ __launch_bounds__(256, 2)
void kmain(const float* __restrict__ x, const float* __restrict__ mean,
           const float* __restrict__ cent, const unsigned short* __restrict__ img,
           float* __restrict__ out,
           unsigned int* __restrict__ counter, unsigned int* __restrict__ list)
{
  __shared__ __align__(16) unsigned short Xh[2][32*128];
  __shared__ __align__(16) unsigned short Xl[2][32*128];
  __shared__ __align__(16) unsigned short Qh[2][32*128];
  __shared__ __align__(16) unsigned short Ql[2][32*128];
  __shared__ float norms[4][32];     // per-wave private
  __shared__ float invs[4][32];

  const int tid = threadIdx.x, lane = tid & 63, w = tid >> 6;
  const int al = lane & 31, ah = lane >> 5;

  short8 B1h[8], B1l[8], B2h[8], B2l[8];
  #pragma unroll
  for (int t = 0; t < 8; ++t) {
    size_t o = (size_t)((w*8 + t)*64 + lane)*8;
    B1h[t] = *(const short8*)(img +         o);
    B1l[t] = *(const short8*)(img + 16384 + o);
    B2h[t] = *(const short8*)(img + 32768 + o);
    B2l[t] = *(const short8*)(img + 49152 + o);
  }

  const float c0 = cent[0], c1 = cent[1], c2 = cent[2], c3 = cent[3];
  const float c4 = cent[4], c5 = cent[5], c6 = cent[6], c7 = cent[7];
  const float mid0 = 0.5f*(c0+c1), mid1 = 0.5f*(c1+c2), mid2 = 0.5f*(c2+c3),
              mid3 = 0.5f*(c3+c4), mid4 = 0.5f*(c4+c5), mid5 = 0.5f*(c5+c6),
              mid6 = 0.5f*(c6+c7);
  unsigned qt0, qt1, qt2, qt3, qt4, qt5, qt6, qt7;
  {
    #define PS(C, QT) { unsigned h = f2bf(C); float hf = __uint_as_float(h<<16); \
                        QT = (h<<16) | f2bf((C) - hf); }
    PS(c0,qt0) PS(c1,qt1) PS(c2,qt2) PS(c3,qt3)
    PS(c4,qt4) PS(c5,qt5) PS(c6,qt6) PS(c7,qt7)
    #undef PS
  }

  const float2 mean2 = *(const float2*)(mean + 2*lane);
  const float meanv = mean[w*32 + al];

  const int row0 = blockIdx.x * 256;

  float2 xpf[8];
  #pragma unroll
  for (int rr = 0; rr < 8; ++rr)
    xpf[rr] = *(const float2*)(x + (size_t)(row0 + w*8 + rr)*128 + 2*lane);

  const bool own = (((al >> 2) & 1) == ah);
  const int rrq = al - 4*ah;
  const int gsel = (rrq & 3) + 4*(rrq >> 3);

  for (int ch = 0; ch < 8; ++ch) {
    const int chb = row0 + ch*32;
    const int p = ch & 1;

    // ---- Phase A: issue next-chunk loads; cvt_pk split -> X[p] ----
    float2 xn[8];
    if (ch < 7) {
      #pragma unroll
      for (int rr = 0; rr < 8; ++rr)
        xn[rr] = *(const float2*)(x + (size_t)(chb + 32 + w*8 + rr)*128 + 2*lane);
    }
    #pragma unroll
    for (int rr = 0; rr < 8; ++rr) {
      const int r = w*8 + rr;
      float a = xpf[rr].x - mean2.x;
      float b = xpf[rr].y - mean2.y;
      unsigned ph, pl;
      asm("v_cvt_pk_bf16_f32 %0, %1, %2" : "=v"(ph) : "v"(a), "v"(b));
      float ha = __uint_as_float(ph << 16);
      float hb = __uint_as_float(ph & 0xFFFF0000u);
      float ra = a - ha, rb = b - hb;
      asm("v_cvt_pk_bf16_f32 %0, %1, %2" : "=v"(pl) : "v"(ra), "v"(rb));
      unsigned off = ((unsigned)(r*256 + 4*lane)) ^ (((unsigned)(r & 7)) << 4);
      *(unsigned*)((char*)&Xh[p][0] + off) = ph;
      *(unsigned*)((char*)&Xl[p][0] + off) = pl;
    }
    #pragma unroll
    for (int rr = 0; rr < 8; ++rr) xpf[rr] = xn[rr];
    LGKM_BAR();                                       // bar1: X[p] ready

    // ---- Phase B: norm-MFMA + mm1, quantize, write Q[p] ----
    f32x16 accN, accA, accB;
    #pragma unroll
    for (int g = 0; g < 16; ++g) { accN[g] = 0.0f; accA[g] = 0.0f; accB[g] = 0.0f; }
    __builtin_amdgcn_s_setprio(1);
    #pragma unroll
    for (int t = 0; t < 8; ++t) {
      unsigned fb = ((unsigned)(al*256 + t*32 + ah*16)) ^ (((unsigned)(al & 7)) << 4);
      short8 xh = *(const short8*)((const char*)&Xh[p][0] + fb);
      short8 xl = *(const short8*)((const char*)&Xl[p][0] + fb);
      accN = __builtin_amdgcn_mfma_f32_32x32x16_bf16(xh, xh, accN, 0, 0, 0);
      accN = __builtin_amdgcn_mfma_f32_32x32x16_bf16(xl, xh, accN, 0, 0, 0);
      accN = __builtin_amdgcn_mfma_f32_32x32x16_bf16(xh, xl, accN, 0, 0, 0);
      if (t & 1) { MM3(accB, xh, xl, B1h[t], B1l[t]); }
      else       { MM3(accA, xh, xl, B1h[t], B1l[t]); }
    }
    __builtin_amdgcn_s_setprio(0);
    #pragma unroll
    for (int g = 0; g < 16; ++g) accA[g] += accB[g];

    // diag -> norms/invs (per-wave LDS broadcast)
    {
      float s2 = accN[0];
      #pragma unroll
      for (int e = 1; e < 16; ++e) s2 = (gsel == e) ? accN[e] : s2;
      if (own) {
        float n = fmaxf(sqrtf(s2), 1e-8f);
        norms[w][al] = n;
        invs[w][al]  = 1.0f / n;
      }
    }
    asm volatile("s_waitcnt lgkmcnt(0)" ::: "memory");

    unsigned qp[16];
    unsigned flags = 0;
    #pragma unroll
    for (int g = 0; g < 16; ++g) {
      const int r = (g & 3) + 8*(g >> 2) + 4*ah;
      float xr = accA[g] * invs[w][r];
      unsigned q = qt0;
      q = (xr > mid0) ? qt1 : q;  q = (xr > mid1) ? qt2 : q;
      q = (xr > mid2) ? qt3 : q;  q = (xr > mid3) ? qt4 : q;
      q = (xr > mid4) ? qt5 : q;  q = (xr > mid5) ? qt6 : q;
      q = (xr > mid6) ? qt7 : q;
      float dm = fabsf(xr - mid0);
      dm = fminf(dm, fabsf(xr - mid1)); dm = fminf(dm, fabsf(xr - mid2));
      dm = fminf(dm, fabsf(xr - mid3)); dm = fminf(dm, fabsf(xr - mid4));
      dm = fminf(dm, fabsf(xr - mid5)); dm = fminf(dm, fabsf(xr - mid6));
      qp[g] = q;
      flags |= (dm < MARGIN) ? (1u << g) : 0u;
    }
    #pragma unroll
    for (int g = 0; g < 16; ++g) {
      const int rq = (g & 3) + 8*(g >> 2) + 4*ah;
      unsigned off = ((unsigned)(rq*256 + (w*32 + al)*2)) ^ (((unsigned)(rq & 7)) << 4);
      *(unsigned short*)((char*)&Qh[p][0] + off) = (unsigned short)(qp[g] >> 16);
      *(unsigned short*)((char*)&Ql[p][0] + off) = (unsigned short)(qp[g] & 0xFFFFu);
    }
    if (__builtin_amdgcn_ballot_w64(flags != 0)) {   // rare path
      #pragma unroll
      for (int g = 0; g < 16; ++g) {
        unsigned long long b = __ballot((flags >> g) & 1u);
        if (b) {
          const int rq = (g & 3) + 8*(g >> 2) + 4*ah;
          unsigned base = 0;
          if (lane == 0) base = atomicAdd(counter, (unsigned)__popcll(b));
          base = (unsigned)__shfl((int)base, 0);
          if ((flags >> g) & 1u) {
            unsigned pp = base + (unsigned)__popcll(b & ((1ull << lane) - 1ull));
            if (pp < LIST_CAP) list[pp] = (unsigned)(chb + rq);
          }
        }
      }
    }
    LGKM_BAR();                                       // bar2: Q[p] ready

    // ---- Phase C: mm2 (Q[p] x B2 regs), scale + store ----
    f32x16 acc2, acc3;
    #pragma unroll
    for (int g = 0; g < 16; ++g) { acc2[g] = 0.0f; acc3[g] = 0.0f; }
    __builtin_amdgcn_s_setprio(1);
    #pragma unroll
    for (int t = 0; t < 8; ++t) {
      unsigned fb = ((unsigned)(al*256 + t*32 + ah*16)) ^ (((unsigned)(al & 7)) << 4);
      short8 xh = *(const short8*)((const char*)&Qh[p][0] + fb);
      short8 xl = *(const short8*)((const char*)&Ql[p][0] + fb);
      if (t & 1) { MM3(acc3, xh, xl, B2h[t], B2l[t]); }
      else       { MM3(acc2, xh, xl, B2h[t], B2l[t]); }
    }
    __builtin_amdgcn_s_setprio(0);

    #pragma unroll
    for (int g = 0; g < 16; ++g) {
      const int rq = (g & 3) + 8*(g >> 2) + 4*ah;
      float o = fmaf(acc2[g] + acc3[g], norms[w][rq], meanv);
      out[(size_t)(chb + rq)*128 + w*32 + al] = o;
    }
  }
}

// =======================================================================
// K_fix: exact f64 recompute of rows with any element within MARGIN of
// a quantization midpoint. One wave per row; overwrites out.
// =======================================================================
__global__ __launch_bounds__(256)
void kfix(const float* __restrict__ x, const float* __restrict__ mean,
          const float* __restrict__ cent, const double* __restrict__ Rt64,
          float* __restrict__ out,
          const unsigned int* __restrict__ counter,
          const unsigned int* __restrict__ list)
{
  __shared__ double xs[4][128];
  __shared__ double qs[4][128];
  const int tid = threadIdx.x, lane = tid & 63, w = tid >> 6;

  unsigned cnt = *counter;
  if (cnt > LIST_CAP) cnt = LIST_CAP;

  const double cc0 = (double)cent[0], cc1 = (double)cent[1], cc2 = (double)cent[2],
               cc3 = (double)cent[3], cc4 = (double)cent[4], cc5 = (double)cent[5],
               cc6 = (double)cent[6], cc7 = (double)cent[7];
  const double m0 = 0.5*(cc0+cc1), m1 = 0.5*(cc1+cc2), m2 = 0.5*(cc2+cc3),
               m3 = 0.5*(cc3+cc4), m4 = 0.5*(cc4+cc5), m5 = 0.5*(cc5+cc6),
               m6 = 0.5*(cc6+cc7);

  const unsigned gw = blockIdx.x*4 + w, stride = gridDim.x*4;
  for (unsigned e = gw; e < cnt; e += stride) {
    const int row = (int)list[e];
    const float* xr = x + (size_t)row*128;
    const int j0 = 2*lane;

    double a = (double)xr[j0]   - (double)mean[j0];
    double b = (double)xr[j0+1] - (double)mean[j0+1];
    double s = a*a + b*b;
    s += __shfl_xor(s, 1);  s += __shfl_xor(s, 2);  s += __shfl_xor(s, 4);
    s += __shfl_xor(s, 8);  s += __shfl_xor(s, 16); s += __shfl_xor(s, 32);
    double n = sqrt(s);
    if (n < 1e-8) n = 1e-8;
    double inv = 1.0 / n;
    xs[w][j0]   = a * inv;
    xs[w][j0+1] = b * inv;
    asm volatile("s_waitcnt lgkmcnt(0)" ::: "memory");

    double acc0 = 0.0, acc1 = 0.0;
    for (int j = 0; j < 128; ++j) {
      double xj = xs[w][j];
      acc0 = fma(xj, Rt64[j*128 + j0],     acc0);
      acc1 = fma(xj, Rt64[j*128 + j0 + 1], acc1);
    }
    double q0 = cc0;
    q0 = (acc0 > m0) ? cc1 : q0;  q0 = (acc0 > m1) ? cc2 : q0;
    q0 = (acc0 > m2) ? cc3 : q0;  q0 = (acc0 > m3) ? cc4 : q0;
    q0 = (acc0 > m4) ? cc5 : q0;  q0 = (acc0 > m5) ? cc6 : q0;
    q0 = (acc0 > m6) ? cc7 : q0;
    double q1 = cc0;
    q1 = (acc1 > m0) ? cc1 : q1;  q1 = (acc1 > m1) ? cc2 : q1;
    q1 = (acc1 > m2) ? cc3 : q1;  q1 = (acc1 > m3) ? cc4 : q1;
    q1 = (acc1 > m4) ? cc5 : q1;  q1 = (acc1 > m5) ? cc6 : q1;
    q1 = (acc1 > m6) ? cc7 : q1;
    qs[w][j0]   = q0;
    qs[w][j0+1] = q1;
    asm volatile("s_waitcnt lgkmcnt(0)" ::: "memory");

    double o0 = 0.0, o1 = 0.0;
    for (int k = 0; k < 128; ++k) {
      double qk = qs[w][k];
      o0 = fma(qk, Rt64[j0*128 + k],       o0);
      o1 = fma(qk, Rt64[(j0+1)*128 + k],   o1);
    }
    out[(size_t)row*128 + j0]   = (float)fma(o0, n, (double)mean[j0]);
    out[(size_t)row*128 + j0+1] = (float)fma(o1, n, (double)mean[j0+1]);
  }
}

// =======================================================================
extern "C" void kernel_launch(void* const* d_in, const int* in_sizes, int n_in,
                              void* d_out, int out_size, void* d_ws, size_t ws_size,
                              hipStream_t stream)
{
  (void)in_sizes; (void)n_in; (void)out_size; (void)ws_size;
  const float* x    = (const float*)d_in[0];
  const float* skew = (const float*)d_in[1];
  const float* cent = (const float*)d_in[2];
  const float* mean = (const float*)d_in[3];
  float* out = (float*)d_out;

  char* ws = (char*)d_ws;
  double*         Rt64 = (double*)(ws);
  unsigned short* img  = (unsigned short*)(ws + 131072);
  unsigned int*   cntr = (unsigned int*)(ws + 262144);
  unsigned int*   list = (unsigned int*)(ws + 262912);
  double*         M64  = (double*)(ws + 4457216);
  double*         Y64  = (double*)(ws + 4588288);
  double*         Yb   = (double*)(ws + 4719360);

  kpre32<<<dim3(1),    dim3(1024), 0, stream>>>(skew, M64, Y64, cntr);
  kref  <<<dim3(8),    dim3(256),  0, stream>>>(M64, Y64, Yb, Rt64, img, 0);
  kref  <<<dim3(8),    dim3(256),  0, stream>>>(M64, Yb, Y64, Rt64, img, 1);
  kmain <<<dim3(1024), dim3(256),  0, stream>>>(x, mean, cent, img, out, cntr, list);
  kfix  <<<dim3(256),  dim3(256),  0, stream>>>(x, mean, cent, Rt64, out, cntr, list);
}